// Round 4
// baseline (89.332 us; speedup 1.0000x reference)
//
#include <hip/hip_runtime.h>

#define BSZ 512
#define NN 128
#define HEADS 8
#define DIN 64
#define DOUT 64

typedef __bf16 bf16x8 __attribute__((ext_vector_type(8)));
typedef float floatx4 __attribute__((ext_vector_type(4)));

static __device__ __forceinline__ unsigned short f2bf(float f) {
    __bf16 b = (__bf16)f;
    return __builtin_bit_cast(unsigned short, b);
}
static __device__ __forceinline__ bf16x8 ld_frag(const unsigned short* p) {
    uint4 r = *reinterpret_cast<const uint4*>(p);
    return __builtin_bit_cast(bf16x8, r);
}

// one block per (b, head); 512 threads = 8 waves; ONE barrier per block
__global__ __launch_bounds__(512, 6) void gat_fwd(
    const float* __restrict__ hin,    // [BSZ][NN][DIN]
    const int*   __restrict__ adj,    // [BSZ][NN][NN]
    const float* __restrict__ w,      // [HEADS][DIN][DOUT]
    const float* __restrict__ a_src,  // [HEADS][DOUT]
    const float* __restrict__ a_dst,  // [HEADS][DOUT]
    const float* __restrict__ bias,   // [DOUT]
    float* __restrict__ out)          // [BSZ][HEADS][NN][DOUT]
{
    // tiles XOR-swizzled: elem_idx ^= (row&7)<<3  (16B chunk swizzle)
    __shared__ __attribute__((aligned(16))) unsigned short hpT[DOUT * NN];    // 16 KB [o][j]
    __shared__ __attribute__((aligned(16))) unsigned short P[NN * NN];        // 32 KB [i][j] bf16 e-vals
    __shared__ __attribute__((aligned(16))) unsigned int   msk[NN * 4];       // 2 KB  row bitmasks
    __shared__ __attribute__((aligned(16))) float s_src[NN];
    __shared__ __attribute__((aligned(16))) float s_dst[NN];

    const int bid  = blockIdx.x;
    const int hd   = bid >> 9;    // slow-varying: concurrent blocks share adj[b]/h[b] in cache
    const int b    = bid & 511;
    const int tid  = threadIdx.x;
    const int lane = tid & 63;
    const int wv   = tid >> 6;    // 0..7
    const int lg   = lane >> 4;   // 0..3
    const int lm   = lane & 15;   // 0..15
    const int n0   = wv * 16;

    // ---- h A-fragments straight to registers (L3-resident) ----
    const float* hb = hin + (size_t)b * NN * DIN;
    bf16x8 hA[2];
    #pragma unroll
    for (int kt = 0; kt < 2; ++kt) {
        const float* p = hb + (n0 + lm) * DIN + kt * 32 + lg * 8;
        float4 v0 = *reinterpret_cast<const float4*>(p);
        float4 v1 = *reinterpret_cast<const float4*>(p + 4);
        bf16x8 a;
        a[0] = (__bf16)v0.x; a[1] = (__bf16)v0.y; a[2] = (__bf16)v0.z; a[3] = (__bf16)v0.w;
        a[4] = (__bf16)v1.x; a[5] = (__bf16)v1.y; a[6] = (__bf16)v1.z; a[7] = (__bf16)v1.w;
        hA[kt] = a;
    }

    // ---- own-wave adjacency bitmasks: lane -> (row n0+(lane>>2), word lane&3) ----
    {
        const int row = n0 + (lane >> 2);
        const int wd  = lane & 3;
        const int* ap = adj + (size_t)b * NN * NN + row * NN + wd * 32;
        unsigned int m = 0;
        #pragma unroll
        for (int t = 0; t < 8; ++t) {
            int4 v = *reinterpret_cast<const int4*>(ap + t * 4);
            m |= (v.x != 0 ? (1u << (4 * t + 0)) : 0u)
               | (v.y != 0 ? (1u << (4 * t + 1)) : 0u)
               | (v.z != 0 ? (1u << (4 * t + 2)) : 0u)
               | (v.w != 0 ? (1u << (4 * t + 3)) : 0u);
        }
        msk[row * 4 + wd] = m;   // written pre-barrier, read post-barrier
    }

    // ======== phase 1: GEMM1 (w frags per-lane from global, L1-hit) ========
    const float* wg = w + hd * DIN * DOUT;
    floatx4 acc[4] = {floatx4{0,0,0,0}, floatx4{0,0,0,0}, floatx4{0,0,0,0}, floatx4{0,0,0,0}};
    #pragma unroll
    for (int kt = 0; kt < 2; ++kt) {
        #pragma unroll
        for (int nt = 0; nt < 4; ++nt) {
            const float* wp = wg + (kt * 32 + lg * 8) * DOUT + nt * 16 + lm;
            bf16x8 bfr;
            #pragma unroll
            for (int q = 0; q < 8; ++q) bfr[q] = (__bf16)wp[q * DOUT];
            acc[nt] = __builtin_amdgcn_mfma_f32_16x16x32_bf16(hA[kt], bfr, acc[nt], 0, 0, 0);
        }
    }
    // tanh -> src/dst partial dots; hp -> hpT (bf16, transposed, swizzled)
    const float* asp = a_src + hd * DOUT;
    const float* adp = a_dst + hd * DOUT;
    float ps[4] = {0, 0, 0, 0}, pd[4] = {0, 0, 0, 0};
    #pragma unroll
    for (int nt = 0; nt < 4; ++nt) {
        const int o = nt * 16 + lm;
        const float as = asp[o], ad = adp[o];
        #pragma unroll
        for (int r = 0; r < 4; ++r) {
            const float v = acc[nt][r];
            const float ex = __expf(2.f * v);
            const float t = 1.f - 2.f / (ex + 1.f);   // tanh, exact formula
            ps[r] = fmaf(t, as, ps[r]);
            pd[r] = fmaf(t, ad, pd[r]);
        }
        const int jb = n0 + lg * 4;
        unsigned int u01 = f2bf(acc[nt][0]) | ((unsigned int)f2bf(acc[nt][1]) << 16);
        unsigned int u23 = f2bf(acc[nt][2]) | ((unsigned int)f2bf(acc[nt][3]) << 16);
        const int base = (o * 128 + jb) ^ ((o & 7) << 3);
        *reinterpret_cast<unsigned int*>(&hpT[base])     = u01;
        *reinterpret_cast<unsigned int*>(&hpT[base + 2]) = u23;
    }
    #pragma unroll
    for (int r = 0; r < 4; ++r) {
        #pragma unroll
        for (int m = 1; m <= 8; m <<= 1) {
            ps[r] += __shfl_xor(ps[r], m);
            pd[r] += __shfl_xor(pd[r], m);
        }
    }
    if (lm == 0) {
        #pragma unroll
        for (int r = 0; r < 4; ++r) {
            s_src[n0 + lg * 4 + r] = ps[r];
            s_dst[n0 + lg * 4 + r] = pd[r];
        }
    }
    __syncthreads();   // the only barrier

    // ======== phase 2: sparse max-free softmax + GEMM2 (per-wave rows) ========
    const int i = n0 + lm;                 // this lane's row (4 lanes/row, lg = j-word)
    const int sw = (i & 7) << 3;
    const float si = s_src[i];

    // zero my 32-col segment of P (4x 16B, swizzled chunks)
    const int pz = i * 128 + lg * 32;
    #pragma unroll
    for (int t = 0; t < 4; ++t)
        *reinterpret_cast<uint4*>(&P[(pz + 8 * t) ^ sw]) = make_uint4(0, 0, 0, 0);

    // bit-scan scatter: only ~6% of entries are unmasked
    unsigned int m = msk[i * 4 + lg];
    float sum = 0.f;
    while (m) {
        const int q = __builtin_ctz(m); m &= m - 1;
        const float x = si + s_dst[lg * 32 + q];
        const float xl = fmaxf(x, 0.f) + 0.2f * fminf(x, 0.f);  // leaky
        const float e = __expf(xl);                              // max-free: x bounded
        const __bf16 eb = (__bf16)e;
        sum += (float)eb;                                        // sum of quantized e
        P[(pz + q) ^ sw] = __builtin_bit_cast(unsigned short, eb);
    }
    sum += __shfl_xor(sum, 16);
    sum += __shfl_xor(sum, 32);
    const float inv = 1.f / sum;

    floatx4 oacc[4] = {floatx4{0,0,0,0}, floatx4{0,0,0,0}, floatx4{0,0,0,0}, floatx4{0,0,0,0}};
    #pragma unroll
    for (int kt = 0; kt < 4; ++kt) {
        const bf16x8 af = ld_frag(&P[(i * 128 + kt * 32 + lg * 8) ^ sw]);
        #pragma unroll
        for (int nt = 0; nt < 4; ++nt) {
            const int o = nt * 16 + lm;
            bf16x8 bfr = ld_frag(&hpT[(o * 128 + kt * 32 + lg * 8) ^ ((o & 7) << 3)]);
            oacc[nt] = __builtin_amdgcn_mfma_f32_16x16x32_bf16(af, bfr, oacc[nt], 0, 0, 0);
        }
    }
    float invr[4];
    #pragma unroll
    for (int r = 0; r < 4; ++r) invr[r] = __shfl(inv, lg * 4 + r);

    float* outb = out + ((size_t)b * HEADS + hd) * NN * DOUT;
    #pragma unroll
    for (int nt = 0; nt < 4; ++nt) {
        const int o = nt * 16 + lm;
        const float bo = bias[o];
        #pragma unroll
        for (int r = 0; r < 4; ++r) {
            const int row = n0 + lg * 4 + r;
            outb[row * DOUT + o] = fmaf(oacc[nt][r], invr[r], bo);
        }
    }
}

extern "C" void kernel_launch(void* const* d_in, const int* in_sizes, int n_in,
                              void* d_out, int out_size, void* d_ws, size_t ws_size,
                              hipStream_t stream) {
    (void)in_sizes; (void)n_in; (void)out_size; (void)d_ws; (void)ws_size;
    const float* h     = (const float*)d_in[0];
    const int*   adj   = (const int*)d_in[1];
    const float* w     = (const float*)d_in[2];
    const float* a_src = (const float*)d_in[3];
    const float* a_dst = (const float*)d_in[4];
    const float* bias  = (const float*)d_in[5];
    float* out = (float*)d_out;
    gat_fwd<<<dim3(BSZ * HEADS), dim3(512), 0, stream>>>(h, adj, w, a_src, a_dst, bias, out);
}

// Round 5
// 71.743 us; speedup vs baseline: 1.2452x; 1.2452x over previous
//
#include <hip/hip_runtime.h>

#define BSZ 512
#define NN 128
#define HEADS 8
#define DIN 64
#define DOUT 64

typedef __bf16 bf16x8 __attribute__((ext_vector_type(8)));
typedef float floatx4 __attribute__((ext_vector_type(4)));

static __device__ __forceinline__ unsigned short f2bf(float f) {
    __bf16 b = (__bf16)f;
    return __builtin_bit_cast(unsigned short, b);
}
static __device__ __forceinline__ bf16x8 ld_frag(const unsigned short* p) {
    uint4 r = *reinterpret_cast<const uint4*>(p);
    return __builtin_bit_cast(bf16x8, r);
}

// ---- kernel A: pack adj[b] (64 KB int32) -> 128-bit row masks (2 KB) ----
__global__ __launch_bounds__(512) void pack_adj(
    const int* __restrict__ adj, unsigned int* __restrict__ msk)
{
    const int b = blockIdx.x;
    const int t = threadIdx.x;          // 0..511: row = t>>2, word = t&3
    const int* ap = adj + (size_t)b * NN * NN + (t >> 2) * NN + (t & 3) * 32;
    unsigned int m = 0;
    #pragma unroll
    for (int q = 0; q < 8; ++q) {
        int4 v = *reinterpret_cast<const int4*>(ap + q * 4);
        m |= (v.x != 0 ? (1u << (4 * q + 0)) : 0u)
           | (v.y != 0 ? (1u << (4 * q + 1)) : 0u)
           | (v.z != 0 ? (1u << (4 * q + 2)) : 0u)
           | (v.w != 0 ? (1u << (4 * q + 3)) : 0u);
    }
    msk[b * 512 + t] = m;
}

// ---- kernel B: one block per (b, head); 512 threads; ONE barrier ----
__global__ __launch_bounds__(512, 6) void gat_fwd(
    const float* __restrict__ hin,    // [BSZ][NN][DIN]
    const unsigned int* __restrict__ mskg,  // [BSZ][NN][4]
    const float* __restrict__ w,      // [HEADS][DIN][DOUT]
    const float* __restrict__ a_src,  // [HEADS][DOUT]
    const float* __restrict__ a_dst,  // [HEADS][DOUT]
    const float* __restrict__ bias,   // [DOUT]
    float* __restrict__ out)          // [BSZ][HEADS][NN][DOUT]
{
    // tiles XOR-swizzled: elem_idx ^= (row&7)<<3  (16B chunk swizzle)
    __shared__ __attribute__((aligned(16))) unsigned short hpT[DOUT * NN];    // 16 KB [o][j]
    __shared__ __attribute__((aligned(16))) unsigned short P[NN * NN];        // 32 KB [i][j] bf16
    __shared__ __attribute__((aligned(16))) float s_src[NN];
    __shared__ __attribute__((aligned(16))) float s_dst[NN];

    const int bid  = blockIdx.x;
    const int b    = bid >> 3;    // hd fast-varying: the 8 head-blocks of b share h[b]/msk[b]
    const int hd   = bid & 7;
    const int tid  = threadIdx.x;
    const int lane = tid & 63;
    const int wv   = tid >> 6;    // 0..7
    const int lg   = lane >> 4;   // 0..3
    const int lm   = lane & 15;   // 0..15
    const int n0   = wv * 16;

    // ---- h A-fragments straight to registers (L3-resident re-read) ----
    const float* hb = hin + (size_t)b * NN * DIN;
    bf16x8 hA[2];
    #pragma unroll
    for (int kt = 0; kt < 2; ++kt) {
        const float* p = hb + (n0 + lm) * DIN + kt * 32 + lg * 8;
        float4 v0 = *reinterpret_cast<const float4*>(p);
        float4 v1 = *reinterpret_cast<const float4*>(p + 4);
        bf16x8 a;
        a[0] = (__bf16)v0.x; a[1] = (__bf16)v0.y; a[2] = (__bf16)v0.z; a[3] = (__bf16)v0.w;
        a[4] = (__bf16)v1.x; a[5] = (__bf16)v1.y; a[6] = (__bf16)v1.z; a[7] = (__bf16)v1.w;
        hA[kt] = a;
    }
    // this lane's softmax mask word (row i = n0+lm, j-word lg) — 4B/lane, one segment
    const unsigned int mw = mskg[b * 512 + (n0 + lm) * 4 + lg];

    // ======== phase 1: GEMM1 (w frags per-lane from global, L1/L2-hit) ========
    const float* wg = w + hd * DIN * DOUT;
    floatx4 acc[4] = {floatx4{0,0,0,0}, floatx4{0,0,0,0}, floatx4{0,0,0,0}, floatx4{0,0,0,0}};
    #pragma unroll
    for (int kt = 0; kt < 2; ++kt) {
        #pragma unroll
        for (int nt = 0; nt < 4; ++nt) {
            const float* wp = wg + (kt * 32 + lg * 8) * DOUT + nt * 16 + lm;
            bf16x8 bfr;
            #pragma unroll
            for (int q = 0; q < 8; ++q) bfr[q] = (__bf16)wp[q * DOUT];
            acc[nt] = __builtin_amdgcn_mfma_f32_16x16x32_bf16(hA[kt], bfr, acc[nt], 0, 0, 0);
        }
    }
    // tanh -> src/dst partial dots; hp -> hpT (bf16, transposed, swizzled)
    const float* asp = a_src + hd * DOUT;
    const float* adp = a_dst + hd * DOUT;
    float ps[4] = {0, 0, 0, 0}, pd[4] = {0, 0, 0, 0};
    #pragma unroll
    for (int nt = 0; nt < 4; ++nt) {
        const int o = nt * 16 + lm;
        const float as = asp[o], ad = adp[o];
        #pragma unroll
        for (int r = 0; r < 4; ++r) {
            const float v = acc[nt][r];
            const float ex = __expf(2.f * v);
            const float t = 1.f - 2.f / (ex + 1.f);   // tanh, exact formula
            ps[r] = fmaf(t, as, ps[r]);
            pd[r] = fmaf(t, ad, pd[r]);
        }
        const int jb = n0 + lg * 4;
        unsigned int u01 = f2bf(acc[nt][0]) | ((unsigned int)f2bf(acc[nt][1]) << 16);
        unsigned int u23 = f2bf(acc[nt][2]) | ((unsigned int)f2bf(acc[nt][3]) << 16);
        const int base = (o * 128 + jb) ^ ((o & 7) << 3);
        *reinterpret_cast<unsigned int*>(&hpT[base])     = u01;
        *reinterpret_cast<unsigned int*>(&hpT[base + 2]) = u23;
    }
    #pragma unroll
    for (int r = 0; r < 4; ++r) {
        #pragma unroll
        for (int m = 1; m <= 8; m <<= 1) {
            ps[r] += __shfl_xor(ps[r], m);
            pd[r] += __shfl_xor(pd[r], m);
        }
    }
    if (lm == 0) {
        #pragma unroll
        for (int r = 0; r < 4; ++r) {
            s_src[n0 + lg * 4 + r] = ps[r];
            s_dst[n0 + lg * 4 + r] = pd[r];
        }
    }
    __syncthreads();   // the only barrier

    // ======== phase 2: sparse max-free softmax + GEMM2 (per-wave rows) ========
    const int i = n0 + lm;                 // this lane's row (4 lanes/row, lg = j-word)
    const int sw = (i & 7) << 3;
    const float si = s_src[i];

    // zero my 32-col segment of P (4x 16B, swizzled chunks)
    const int pz = i * 128 + lg * 32;
    #pragma unroll
    for (int t = 0; t < 4; ++t)
        *reinterpret_cast<uint4*>(&P[(pz + 8 * t) ^ sw]) = make_uint4(0, 0, 0, 0);

    // bit-scan scatter: only ~6% of entries are unmasked
    unsigned int m = mw;
    float sum = 0.f;
    while (m) {
        const int q = __builtin_ctz(m); m &= m - 1;
        const float x = si + s_dst[lg * 32 + q];
        const float xl = fmaxf(x, 0.f) + 0.2f * fminf(x, 0.f);  // leaky
        const float e = __expf(xl);                              // max-free: x bounded
        const __bf16 eb = (__bf16)e;
        sum += (float)eb;                                        // sum of quantized e
        P[(pz + q) ^ sw] = __builtin_bit_cast(unsigned short, eb);
    }
    sum += __shfl_xor(sum, 16);
    sum += __shfl_xor(sum, 32);
    const float inv = 1.f / sum;

    floatx4 oacc[4] = {floatx4{0,0,0,0}, floatx4{0,0,0,0}, floatx4{0,0,0,0}, floatx4{0,0,0,0}};
    #pragma unroll
    for (int kt = 0; kt < 4; ++kt) {
        const bf16x8 af = ld_frag(&P[(i * 128 + kt * 32 + lg * 8) ^ sw]);
        #pragma unroll
        for (int nt = 0; nt < 4; ++nt) {
            const int o = nt * 16 + lm;
            bf16x8 bfr = ld_frag(&hpT[(o * 128 + kt * 32 + lg * 8) ^ ((o & 7) << 3)]);
            oacc[nt] = __builtin_amdgcn_mfma_f32_16x16x32_bf16(af, bfr, oacc[nt], 0, 0, 0);
        }
    }
    float invr[4];
    #pragma unroll
    for (int r = 0; r < 4; ++r) invr[r] = __shfl(inv, lg * 4 + r);

    float* outb = out + ((size_t)b * HEADS + hd) * NN * DOUT;
    #pragma unroll
    for (int nt = 0; nt < 4; ++nt) {
        const int o = nt * 16 + lm;
        const float bo = bias[o];
        #pragma unroll
        for (int r = 0; r < 4; ++r) {
            const int row = n0 + lg * 4 + r;
            outb[row * DOUT + o] = fmaf(oacc[nt][r], invr[r], bo);
        }
    }
}

extern "C" void kernel_launch(void* const* d_in, const int* in_sizes, int n_in,
                              void* d_out, int out_size, void* d_ws, size_t ws_size,
                              hipStream_t stream) {
    (void)in_sizes; (void)n_in; (void)out_size; (void)ws_size;
    const float* h     = (const float*)d_in[0];
    const int*   adj   = (const int*)d_in[1];
    const float* w     = (const float*)d_in[2];
    const float* a_src = (const float*)d_in[3];
    const float* a_dst = (const float*)d_in[4];
    const float* bias  = (const float*)d_in[5];
    float* out = (float*)d_out;
    unsigned int* msk = (unsigned int*)d_ws;   // 512*512*4 = 1 MB
    pack_adj<<<dim3(BSZ), dim3(512), 0, stream>>>(adj, msk);
    gat_fwd<<<dim3(BSZ * HEADS), dim3(512), 0, stream>>>(h, msk, w, a_src, a_dst, bias, out);
}